// Round 3
// baseline (363.280 us; speedup 1.0000x reference)
//
#include <hip/hip_runtime.h>
#include <hip/hip_bf16.h>

typedef short bf16x8 __attribute__((ext_vector_type(8)));
typedef float f32x4 __attribute__((ext_vector_type(4)));

#define NB 16384
#define IN_DIM 512
#define HD 1024
#define NT 512
#define KTILES 48

__device__ __forceinline__ short f2b(float f) {
    __hip_bfloat16 h = __float2bfloat16(f);
    return *reinterpret_cast<short*>(&h);
}

__device__ __forceinline__ void gload16(const void* g, void* l) {
    __builtin_amdgcn_global_load_lds(
        (const __attribute__((address_space(1))) void*)g,
        (__attribute__((address_space(3))) void*)l, 16, 0, 0);
}

// ---------------- prepass: weights -> bf16 swizzled tiles (verified r2) ------
// wsB tiles: [bh 0..15][kt 0..47] each 256 cols x 32 k bf16 (16 KB), row=64B,
// element (cid,k) at byte cid*64 + ((k*2) ^ (((cid>>1)&3)<<4))
__global__ void prep_w(const float* __restrict__ w_w, const float* __restrict__ r_w,
                       short* __restrict__ wsB) {
    const int blk = blockIdx.x;          // bh*48 + kt
    const int kt  = blk % KTILES;
    const int cid = threadIdx.x;         // 0..255
    const int bh  = blk / KTILES;
    const int g   = (cid >> 4) & 3;
    const int jh  = ((cid >> 6) << 4) | (cid & 15);
    const int gcol = g * HD + bh * 64 + jh;

    const float* src = (kt < 16) ? w_w : r_w;
    const int kbase  = (kt < 16) ? kt * 32 : (kt - 16) * 32;

    float v[32];
#pragma unroll
    for (int kk = 0; kk < 32; ++kk)
        v[kk] = src[(size_t)(kbase + kk) * 4096 + gcol];

    char* tile = (char*)(wsB + (size_t)blk * 8192);
    const int swz = ((cid >> 1) & 3) << 4;
#pragma unroll
    for (int s = 0; s < 4; ++s) {
        bf16x8 o;
#pragma unroll
        for (int j = 0; j < 8; ++j) o[j] = f2b(v[s * 8 + j]);
        *(bf16x8*)(tile + cid * 64 + ((s * 16) ^ swz)) = o;
    }
}

// ---------------- prepass: activations -> bf16 swizzled tiles ----------------
// wsA tiles: [bm 0..63][kt 0..47] each 256 rows x 32 k bf16 (16 KB)
__global__ void prep_a(const float* __restrict__ x, const float* __restrict__ h_p,
                       short* __restrict__ wsA) {
    const int blk  = blockIdx.x;         // bm*48 + kt
    const int kt   = blk % KTILES;
    const int bm   = blk / KTILES;
    const int t    = threadIdx.x;        // 0..511
    const int row  = t >> 1;             // 0..255
    const int half = t & 1;
    const int grow = bm * 256 + row;

    const float* src = (kt < 16)
        ? x   + (size_t)grow * IN_DIM + kt * 32 + half * 16
        : h_p + (size_t)grow * HD     + (kt - 16) * 32 + half * 16;

    float4 a0 = ((const float4*)src)[0];
    float4 a1 = ((const float4*)src)[1];
    float4 a2 = ((const float4*)src)[2];
    float4 a3 = ((const float4*)src)[3];
    float v[16] = {a0.x,a0.y,a0.z,a0.w, a1.x,a1.y,a1.z,a1.w,
                   a2.x,a2.y,a2.z,a2.w, a3.x,a3.y,a3.z,a3.w};

    char* tile = (char*)(wsA + (size_t)blk * 8192);
    const int swz = ((row >> 1) & 3) << 4;
#pragma unroll
    for (int s = 0; s < 2; ++s) {
        bf16x8 o;
#pragma unroll
        for (int j = 0; j < 8; ++j) o[j] = f2b(v[s * 8 + j]);
        *(bf16x8*)(tile + row * 64 + ((half * 32 + s * 16) ^ swz)) = o;
    }
}

// ---------------- main fused GEMM + epilogue (256x256, 4-deep pipeline) ------
__global__ __launch_bounds__(NT, 2) void slstm_fused(
    const short* __restrict__ wsA, const short* __restrict__ wsB,
    const float* __restrict__ c_p, const float* __restrict__ n_p,
    const float* __restrict__ m_p, const float* __restrict__ w_b,
    const float* __restrict__ r_b, float* __restrict__ out)
{
    // 4 rotating buffers; each: A-tile shorts [0,8192) + B-tile [8192,16384)
    __shared__ __align__(16) short S[4][16384];   // 128 KiB

    const int t    = threadIdx.x;
    const int lane = t & 63;
    const int wid  = t >> 6;
    const int wm   = wid >> 2;    // 0..1 : 128-row half
    const int wn   = wid & 3;     // 0..3 : 64-col group
    const int l15  = lane & 15;
    const int l4   = lane >> 4;

    // XCD-aware mapping: xcd = b&7 gets 2 bh strips (L2-resident B) and
    // pairs of blocks sharing each bm strip (2-way A reuse).
    const int b   = (int)blockIdx.x;
    const int i   = b >> 3;
    const int bm  = i >> 1;                  // 0..63
    const int bh  = (b & 7) * 2 + (i & 1);   // 0..15

    const short* gA = wsA + (size_t)(bm * KTILES) * 8192 + wid * 512 + lane * 8;
    const short* gB = wsB + (size_t)(bh * KTILES) * 8192 + wid * 512 + lane * 8;
    const int aw = wid * 512;   // LDS dest base (shorts) per wave

    // fragment base offsets (shorts); swizzle term is mi/g-independent
    const int sw  = (l4 * 8) ^ (((l15 >> 1) & 3) << 3);
    const int aoff = (wm * 128 + l15) * 32 + sw;          // + mi*512
    const int boff = 8192 + (wn * 64 + l15) * 32 + sw;    // + g*512

    f32x4 acc[8][4];
    const f32x4 zero = {0.f, 0.f, 0.f, 0.f};
#pragma unroll
    for (int mi = 0; mi < 8; ++mi)
#pragma unroll
        for (int g = 0; g < 4; ++g) acc[mi][g] = zero;

    // prologue: stage K-tiles 0,1,2 (12 loads); wait K-tile 0 resident
#pragma unroll
    for (int kt = 0; kt < 3; ++kt) {
        const short* ga = gA + kt * 8192;
        const short* gb = gB + kt * 8192;
        gload16(ga,        &S[kt][aw]);
        gload16(ga + 4096, &S[kt][aw + 4096]);
        gload16(gb,        &S[kt][8192 + aw]);
        gload16(gb + 4096, &S[kt][8192 + aw + 4096]);
    }
    asm volatile("s_waitcnt vmcnt(8)" ::: "memory");
    __builtin_amdgcn_s_barrier();
    __builtin_amdgcn_sched_barrier(0);

    for (int kt = 0; kt < KTILES; ++kt) {
        const short* Sc = &S[kt & 3][0];
        const int nb = (kt + 3) & 3;          // == (kt-1)&3 : freed last K-tile
        const bool pf = (kt + 3 < KTILES);

        // phase A: issue A-half of K-tile kt+3; frags; MFMA mi 0-3
        if (pf) {
            const short* ga = gA + (size_t)(kt + 3) * 8192;
            gload16(ga,        &S[nb][aw]);
            gload16(ga + 4096, &S[nb][aw + 4096]);
        }
        bf16x8 afr[4], bfr[4];
#pragma unroll
        for (int mi = 0; mi < 4; ++mi) afr[mi] = *(const bf16x8*)&Sc[aoff + mi * 512];
#pragma unroll
        for (int g = 0; g < 4; ++g)    bfr[g]  = *(const bf16x8*)&Sc[boff + g * 512];
        __builtin_amdgcn_s_setprio(1);
#pragma unroll
        for (int mi = 0; mi < 4; ++mi)
#pragma unroll
            for (int g = 0; g < 4; ++g)
                acc[mi][g] = __builtin_amdgcn_mfma_f32_16x16x32_bf16(
                    afr[mi], bfr[g], acc[mi][g], 0, 0, 0);
        __builtin_amdgcn_s_setprio(0);

        // phase B: issue B-half of kt+3; frags mi 4-7 (reuse bfr); MFMA
        if (pf) {
            const short* gb = gB + (size_t)(kt + 3) * 8192;
            gload16(gb,        &S[nb][8192 + aw]);
            gload16(gb + 4096, &S[nb][8192 + aw + 4096]);
        }
        bf16x8 af2[4];
#pragma unroll
        for (int mi = 0; mi < 4; ++mi) af2[mi] = *(const bf16x8*)&Sc[aoff + (mi + 4) * 512];
        __builtin_amdgcn_s_setprio(1);
#pragma unroll
        for (int mi = 0; mi < 4; ++mi)
#pragma unroll
            for (int g = 0; g < 4; ++g)
                acc[mi + 4][g] = __builtin_amdgcn_mfma_f32_16x16x32_bf16(
                    af2[mi], bfr[g], acc[mi + 4][g], 0, 0, 0);
        __builtin_amdgcn_s_setprio(0);

        // K-tile boundary: counted vmcnt guarantees kt+1 resident, then barrier
        if (kt < KTILES - 3)       { asm volatile("s_waitcnt vmcnt(8)" ::: "memory"); }
        else if (kt == KTILES - 3) { asm volatile("s_waitcnt vmcnt(4)" ::: "memory"); }
        else if (kt == KTILES - 2) { asm volatile("s_waitcnt vmcnt(0)" ::: "memory"); }
        __builtin_amdgcn_s_barrier();
        __builtin_amdgcn_sched_barrier(0);
    }

    // ---- fused epilogue: all 4 gates of (row,h) are lane-local ----
    const int h = bh * 64 + wn * 16 + l15;
    float bias[4];
#pragma unroll
    for (int g = 0; g < 4; ++g) bias[g] = w_b[g * HD + h] + r_b[g * HD + h];

    const size_t PL = (size_t)NB * HD;
#pragma unroll
    for (int mi = 0; mi < 8; ++mi) {
#pragma unroll
        for (int r = 0; r < 4; ++r) {
            const int row = bm * 256 + wm * 128 + mi * 16 + l4 * 4 + r;
            const size_t idx = (size_t)row * HD + h;
            const float ci = acc[mi][0][r] + bias[0];
            const float ig = acc[mi][1][r] + bias[1];
            const float fg = acc[mi][2][r] + bias[2];
            const float og = acc[mi][3][r] + bias[3];
            const float mp  = m_p[idx];
            const float cp  = c_p[idx];
            const float np_ = n_p[idx];
            const float z  = tanhf(ci);
            const float it = expf(ig);
            const float mt = fmaxf(fg + mp, ig);
            const float sf = expf(fg + mp - mt);
            const float si = expf(ig - mt);
            const float ct = sf * cp + it * z;
            const float nt = sf * np_ + si;
            const float ot = 1.0f / (1.0f + expf(-og));
            const float ht = ot * (ct / nt);
            out[idx]          = ht;
            out[PL + idx]     = ct;
            out[2 * PL + idx] = ht;
            out[3 * PL + idx] = nt;
            out[4 * PL + idx] = mt;
        }
    }
}

extern "C" void kernel_launch(void* const* d_in, const int* in_sizes, int n_in,
                              void* d_out, int out_size, void* d_ws, size_t ws_size,
                              hipStream_t stream) {
    const float* x   = (const float*)d_in[0];
    const float* c_p = (const float*)d_in[1];
    const float* h_p = (const float*)d_in[2];
    const float* n_p = (const float*)d_in[3];
    const float* m_p = (const float*)d_in[4];
    const float* w_w = (const float*)d_in[5];
    const float* w_b = (const float*)d_in[6];
    const float* r_w = (const float*)d_in[7];
    const float* r_b = (const float*)d_in[8];
    float* out = (float*)d_out;

    short* wsB = (short*)d_ws;                                         // 12.58 MB
    short* wsA = (short*)((char*)d_ws + (size_t)16 * KTILES * 16384);  // 50.33 MB

    prep_w<<<dim3(16 * KTILES), 256, 0, stream>>>(w_w, r_w, wsB);
    prep_a<<<dim3(64 * KTILES), NT, 0, stream>>>(x, h_p, wsA);
    slstm_fused<<<dim3(1024), NT, 0, stream>>>(wsA, wsB, c_p, n_p, m_p, w_b, r_b, out);
}

// Round 4
// 360.791 us; speedup vs baseline: 1.0069x; 1.0069x over previous
//
#include <hip/hip_runtime.h>
#include <hip/hip_bf16.h>

typedef short bf16x8 __attribute__((ext_vector_type(8)));
typedef float f32x4 __attribute__((ext_vector_type(4)));

#define NB 16384
#define IN_DIM 512
#define HD 1024
#define KTILES 48

__device__ __forceinline__ short f2b(float f) {
    __hip_bfloat16 h = __float2bfloat16(f);
    return *reinterpret_cast<short*>(&h);
}

__device__ __forceinline__ void gload16(const void* g, void* l) {
    __builtin_amdgcn_global_load_lds(
        (const __attribute__((address_space(1))) void*)g,
        (__attribute__((address_space(3))) void*)l, 16, 0, 0);
}

// ---------------- prepass: weights -> bf16 swizzled tiles ----------------
// wsB tiles: [bh 0..31][kt 0..47] each 128 cols x 32 k bf16 (8 KB), row=64B,
// element (cid,k) at byte cid*64 + ((k*2) ^ (((cid>>1)&3)<<4))
// cid = wn*64 + g*16 + jh  ->  gcol = g*1024 + bh*32 + wn*16 + jh
__global__ void prep_w(const float* __restrict__ w_w, const float* __restrict__ r_w,
                       short* __restrict__ wsB) {
    const int blk = blockIdx.x;          // bh*48 + kt
    const int kt  = blk % KTILES;
    const int bh  = blk / KTILES;
    const int cid = threadIdx.x;         // 0..127
    const int g   = (cid >> 4) & 3;
    const int gcol = g * HD + bh * 32 + ((cid >> 6) << 4) + (cid & 15);

    const float* src = (kt < 16) ? w_w : r_w;
    const int kbase  = (kt < 16) ? kt * 32 : (kt - 16) * 32;

    float v[32];
#pragma unroll
    for (int kk = 0; kk < 32; ++kk)
        v[kk] = src[(size_t)(kbase + kk) * 4096 + gcol];

    char* tile = (char*)(wsB + (size_t)blk * 4096);
    const int swz = ((cid >> 1) & 3) << 4;
#pragma unroll
    for (int s = 0; s < 4; ++s) {
        bf16x8 o;
#pragma unroll
        for (int j = 0; j < 8; ++j) o[j] = f2b(v[s * 8 + j]);
        *(bf16x8*)(tile + cid * 64 + ((s * 16) ^ swz)) = o;
    }
}

// ---------------- prepass: activations -> bf16 swizzled tiles ----------------
// wsA tiles: [bm 0..127][kt 0..47] each 128 rows x 32 k bf16 (8 KB)
__global__ void prep_a(const float* __restrict__ x, const float* __restrict__ h_p,
                       short* __restrict__ wsA) {
    const int blk  = blockIdx.x;         // bm*48 + kt
    const int kt   = blk % KTILES;
    const int bm   = blk / KTILES;
    const int t    = threadIdx.x;        // 0..255
    const int row  = t >> 1;
    const int half = t & 1;
    const int grow = bm * 128 + row;

    const float* src = (kt < 16)
        ? x   + (size_t)grow * IN_DIM + kt * 32 + half * 16
        : h_p + (size_t)grow * HD     + (kt - 16) * 32 + half * 16;

    float4 a0 = ((const float4*)src)[0];
    float4 a1 = ((const float4*)src)[1];
    float4 a2 = ((const float4*)src)[2];
    float4 a3 = ((const float4*)src)[3];
    float v[16] = {a0.x,a0.y,a0.z,a0.w, a1.x,a1.y,a1.z,a1.w,
                   a2.x,a2.y,a2.z,a2.w, a3.x,a3.y,a3.z,a3.w};

    char* tile = (char*)(wsA + (size_t)blk * 4096);
    const int swz = ((row >> 1) & 3) << 4;
#pragma unroll
    for (int s = 0; s < 2; ++s) {
        bf16x8 o;
#pragma unroll
        for (int j = 0; j < 8; ++j) o[j] = f2b(v[s * 8 + j]);
        *(bf16x8*)(tile + row * 64 + ((half * 32 + s * 16) ^ swz)) = o;
    }
}

// -------- main fused GEMM + epilogue (128x128 tile, 4 waves, 4 blocks/CU) ----
__global__ __launch_bounds__(256, 4) void slstm_fused(
    const short* __restrict__ wsA, const short* __restrict__ wsB,
    const float* __restrict__ c_p, const float* __restrict__ n_p,
    const float* __restrict__ m_p, const float* __restrict__ w_b,
    const float* __restrict__ r_b, float* __restrict__ out)
{
    // double buffer: each buf = A-tile shorts [0,4096) + B-tile [4096,8192)
    __shared__ __align__(16) short S[2][8192];   // 32 KiB

    const int t    = threadIdx.x;
    const int lane = t & 63;
    const int wid  = t >> 6;     // 0..3
    const int wm   = wid >> 1;   // 0..1 : 64-row half
    const int wn   = wid & 1;    // 0..1 : 16-h half
    const int l15  = lane & 15;
    const int l4   = lane >> 4;

    // XCD-bijective mapping: xcd = b&7 owns 4 bh strips (1.5 MB B, L2-resident)
    // and reuses each bm A-strip 4x consecutively.
    const int b  = (int)blockIdx.x;
    const int j  = b >> 3;
    const int bh = (b & 7) * 4 + (j & 3);   // 0..31
    const int bm = j >> 2;                  // 0..127

    const short* gA = wsA + (size_t)(bm * KTILES) * 4096 + t * 8;
    const short* gB = wsB + (size_t)(bh * KTILES) * 4096 + t * 8;

    // fragment base offsets (shorts); swizzle term is mi/g-independent
    const int sw   = (l4 * 8) ^ (((l15 >> 1) & 3) << 3);
    const int aoff = (wm * 64 + l15) * 32 + sw;           // + mi*512
    const int boff = 4096 + (wn * 64 + l15) * 32 + sw;    // + g*512

    // bias folded into accumulator init
    const int h = bh * 32 + wn * 16 + l15;
    f32x4 acc[4][4];
#pragma unroll
    for (int g = 0; g < 4; ++g) {
        const float bias = w_b[g * HD + h] + r_b[g * HD + h];
        const f32x4 binit = {bias, bias, bias, bias};
#pragma unroll
        for (int mi = 0; mi < 4; ++mi) acc[mi][g] = binit;
    }

    // prologue: stage kt=0 into buf 0 (A 2 loads + B 2 loads per thread)
    gload16(gA,        &S[0][wid * 512]);
    gload16(gA + 2048, &S[0][2048 + wid * 512]);
    gload16(gB,        &S[0][4096 + wid * 512]);
    gload16(gB + 2048, &S[0][6144 + wid * 512]);
    __syncthreads();

    int p = 0;
    for (int kt = 0; kt < KTILES; ++kt) {
        if (kt < KTILES - 1) {
            const short* ga = gA + (size_t)(kt + 1) * 4096;
            const short* gb = gB + (size_t)(kt + 1) * 4096;
            gload16(ga,        &S[p ^ 1][wid * 512]);
            gload16(ga + 2048, &S[p ^ 1][2048 + wid * 512]);
            gload16(gb,        &S[p ^ 1][4096 + wid * 512]);
            gload16(gb + 2048, &S[p ^ 1][6144 + wid * 512]);
        }

        bf16x8 af[4], bfr[4];
#pragma unroll
        for (int mi = 0; mi < 4; ++mi) af[mi]  = *(const bf16x8*)&S[p][aoff + mi * 512];
#pragma unroll
        for (int g = 0; g < 4; ++g)    bfr[g]  = *(const bf16x8*)&S[p][boff + g * 512];
#pragma unroll
        for (int mi = 0; mi < 4; ++mi)
#pragma unroll
            for (int g = 0; g < 4; ++g)
                acc[mi][g] = __builtin_amdgcn_mfma_f32_16x16x32_bf16(
                    af[mi], bfr[g], acc[mi][g], 0, 0, 0);

        __syncthreads();   // drains vmcnt(0): next buf staged; buf p free
        p ^= 1;
    }

    // ---- fused epilogue: all 4 gates of (row,h) are lane-local ----
    const size_t PL = (size_t)NB * HD;
#pragma unroll
    for (int mi = 0; mi < 4; ++mi) {
#pragma unroll
        for (int r = 0; r < 4; ++r) {
            const int row = bm * 128 + wm * 64 + mi * 16 + l4 * 4 + r;
            const size_t idx = (size_t)row * HD + h;
            const float ci = acc[mi][0][r];
            const float ig = acc[mi][1][r];
            const float fg = acc[mi][2][r];
            const float og = acc[mi][3][r];
            const float mp  = m_p[idx];
            const float cp  = c_p[idx];
            const float np_ = n_p[idx];
            const float z  = tanhf(ci);
            const float it = expf(ig);
            const float mt = fmaxf(fg + mp, ig);
            const float sf = expf(fg + mp - mt);
            const float si = expf(ig - mt);
            const float ct = sf * cp + it * z;
            const float nt = sf * np_ + si;
            const float ot = 1.0f / (1.0f + expf(-og));
            const float ht = ot * (ct / nt);
            out[idx]          = ht;
            out[PL + idx]     = ct;
            out[2 * PL + idx] = ht;
            out[3 * PL + idx] = nt;
            out[4 * PL + idx] = mt;
        }
    }
}

extern "C" void kernel_launch(void* const* d_in, const int* in_sizes, int n_in,
                              void* d_out, int out_size, void* d_ws, size_t ws_size,
                              hipStream_t stream) {
    const float* x   = (const float*)d_in[0];
    const float* c_p = (const float*)d_in[1];
    const float* h_p = (const float*)d_in[2];
    const float* n_p = (const float*)d_in[3];
    const float* m_p = (const float*)d_in[4];
    const float* w_w = (const float*)d_in[5];
    const float* w_b = (const float*)d_in[6];
    const float* r_w = (const float*)d_in[7];
    const float* r_b = (const float*)d_in[8];
    float* out = (float*)d_out;

    short* wsB = (short*)d_ws;                                        // 12.58 MB
    short* wsA = (short*)((char*)d_ws + (size_t)32 * KTILES * 8192);  // 50.33 MB

    prep_w<<<dim3(32 * KTILES), 128, 0, stream>>>(w_w, r_w, wsB);
    prep_a<<<dim3(128 * KTILES), 256, 0, stream>>>(x, h_p, wsA);
    slstm_fused<<<dim3(4096), 256, 0, stream>>>(wsA, wsB, c_p, n_p, m_p, w_b, r_b, out);
}

// Round 5
// 335.346 us; speedup vs baseline: 1.0833x; 1.0759x over previous
//
#include <hip/hip_runtime.h>
#include <hip/hip_bf16.h>

typedef short bf16x8 __attribute__((ext_vector_type(8)));
typedef float f32x4 __attribute__((ext_vector_type(4)));

#define NB 16384
#define IN_DIM 512
#define HD 1024
#define NT 512
#define KTILES 48

__device__ __forceinline__ short f2b(float f) {
    __hip_bfloat16 h = __float2bfloat16(f);
    return *reinterpret_cast<short*>(&h);
}

__device__ __forceinline__ void gload16(const void* g, void* l) {
    __builtin_amdgcn_global_load_lds(
        (const __attribute__((address_space(1))) void*)g,
        (__attribute__((address_space(3))) void*)l, 16, 0, 0);
}

// ---------------- prepass: weights -> bf16 swizzled tiles (verified r2/r3) ---
// wsB tiles: [bh 0..15][kt 0..47] each 256 cols x 32 k bf16 (16 KB), row=64B,
// element (cid,k) at byte cid*64 + ((k*2) ^ (((cid>>1)&3)<<4))
__global__ void prep_w(const float* __restrict__ w_w, const float* __restrict__ r_w,
                       short* __restrict__ wsB) {
    const int blk = blockIdx.x;          // bh*48 + kt
    const int kt  = blk % KTILES;
    const int cid = threadIdx.x;         // 0..255
    const int bh  = blk / KTILES;
    const int g   = (cid >> 4) & 3;
    const int jh  = ((cid >> 6) << 4) | (cid & 15);
    const int gcol = g * HD + bh * 64 + jh;

    const float* src = (kt < 16) ? w_w : r_w;
    const int kbase  = (kt < 16) ? kt * 32 : (kt - 16) * 32;

    float v[32];
#pragma unroll
    for (int kk = 0; kk < 32; ++kk)
        v[kk] = src[(size_t)(kbase + kk) * 4096 + gcol];

    char* tile = (char*)(wsB + (size_t)blk * 8192);
    const int swz = ((cid >> 1) & 3) << 4;
#pragma unroll
    for (int s = 0; s < 4; ++s) {
        bf16x8 o;
#pragma unroll
        for (int j = 0; j < 8; ++j) o[j] = f2b(v[s * 8 + j]);
        *(bf16x8*)(tile + cid * 64 + ((s * 16) ^ swz)) = o;
    }
}

// ---------------- prepass: activations -> bf16 swizzled tiles (verified r3) --
// wsA tiles: [bm 0..63][kt 0..47] each 256 rows x 32 k bf16 (16 KB)
__global__ void prep_a(const float* __restrict__ x, const float* __restrict__ h_p,
                       short* __restrict__ wsA) {
    const int blk  = blockIdx.x;         // bm*48 + kt
    const int kt   = blk % KTILES;
    const int bm   = blk / KTILES;
    const int t    = threadIdx.x;        // 0..511
    const int row  = t >> 1;             // 0..255
    const int half = t & 1;
    const int grow = bm * 256 + row;

    const float* src = (kt < 16)
        ? x   + (size_t)grow * IN_DIM + kt * 32 + half * 16
        : h_p + (size_t)grow * HD     + (kt - 16) * 32 + half * 16;

    float4 a0 = ((const float4*)src)[0];
    float4 a1 = ((const float4*)src)[1];
    float4 a2 = ((const float4*)src)[2];
    float4 a3 = ((const float4*)src)[3];
    float v[16] = {a0.x,a0.y,a0.z,a0.w, a1.x,a1.y,a1.z,a1.w,
                   a2.x,a2.y,a2.z,a2.w, a3.x,a3.y,a3.z,a3.w};

    char* tile = (char*)(wsA + (size_t)blk * 8192);
    const int swz = ((row >> 1) & 3) << 4;
#pragma unroll
    for (int s = 0; s < 2; ++s) {
        bf16x8 o;
#pragma unroll
        for (int j = 0; j < 8; ++j) o[j] = f2b(v[s * 8 + j]);
        *(bf16x8*)(tile + row * 64 + ((half * 32 + s * 16) ^ swz)) = o;
    }
}

// ---------------- main: persistent, 256x256 tile, counted-vmcnt pipeline -----
__shared__ __align__(16) short S_dummy_decl_guard[1]; // (no-op; keep single TU simple)

template<int VM, bool STAGE>
__device__ __forceinline__ void kstep(short (*S)[16384], int slot,
                                      const short*& stA, const short*& stB,
                                      int aoff, int boff, int wid,
                                      f32x4 (&acc)[8][4]) {
    if constexpr (VM == 8)      asm volatile("s_waitcnt vmcnt(8)" ::: "memory");
    else if constexpr (VM == 4) asm volatile("s_waitcnt vmcnt(4)" ::: "memory");
    else                        asm volatile("s_waitcnt vmcnt(0)" ::: "memory");
    __builtin_amdgcn_s_barrier();
    __builtin_amdgcn_sched_barrier(0);

    const short* Sc = S[slot];
    const int js = (slot + 3) & 3;

    bf16x8 bfr[4], af[4];
#pragma unroll
    for (int g = 0; g < 4; ++g)    bfr[g] = *(const bf16x8*)&Sc[boff + g * 512];
#pragma unroll
    for (int mi = 0; mi < 4; ++mi) af[mi] = *(const bf16x8*)&Sc[aoff + mi * 512];
    if constexpr (STAGE) {
        gload16(stA,        &S[js][wid * 512]);
        gload16(stA + 4096, &S[js][4096 + wid * 512]);
    }
    __builtin_amdgcn_s_setprio(1);
#pragma unroll
    for (int mi = 0; mi < 4; ++mi)
#pragma unroll
        for (int g = 0; g < 4; ++g)
            acc[mi][g] = __builtin_amdgcn_mfma_f32_16x16x32_bf16(
                af[mi], bfr[g], acc[mi][g], 0, 0, 0);
    __builtin_amdgcn_s_setprio(0);

#pragma unroll
    for (int mi = 0; mi < 4; ++mi) af[mi] = *(const bf16x8*)&Sc[aoff + (mi + 4) * 512];
    if constexpr (STAGE) {
        gload16(stB,        &S[js][8192 + wid * 512]);
        gload16(stB + 4096, &S[js][12288 + wid * 512]);
        stA += 8192; stB += 8192;
    }
    __builtin_amdgcn_s_setprio(1);
#pragma unroll
    for (int mi = 0; mi < 4; ++mi)
#pragma unroll
        for (int g = 0; g < 4; ++g)
            acc[mi + 4][g] = __builtin_amdgcn_mfma_f32_16x16x32_bf16(
                af[mi], bfr[g], acc[mi + 4][g], 0, 0, 0);
    __builtin_amdgcn_s_setprio(0);
}

__global__ __launch_bounds__(NT, 2) void slstm_fused(
    const short* __restrict__ wsA, const short* __restrict__ wsB,
    const float* __restrict__ c_p, const float* __restrict__ n_p,
    const float* __restrict__ m_p, const float* __restrict__ w_b,
    const float* __restrict__ r_b, float* __restrict__ out)
{
    __shared__ __align__(16) short S[4][16384];   // 128 KiB, 4 rotating kt-slots

    const int t    = threadIdx.x;
    const int lane = t & 63;
    const int wid  = t >> 6;     // 0..7
    const int wm   = wid >> 2;   // 0..1
    const int wn   = wid & 3;    // 0..3
    const int l15  = lane & 15;
    const int l4   = lane >> 4;

    const int b   = (int)blockIdx.x;   // 0..255, persistent (1/CU)
    const int xcd = b & 7;
    const int li  = b >> 3;            // 0..31

    const int sw   = (l4 * 8) ^ (((l15 >> 1) & 3) << 3);
    const int aoff = (wm * 128 + l15) * 32 + sw;           // + mi*512
    const int boff = 8192 + (wn * 64 + l15) * 32 + sw;     // + g*512

    // two bias sets (bh parity), hoisted
    float bias[2][4];
#pragma unroll
    for (int p = 0; p < 2; ++p) {
        const int hh = (xcd * 2 + p) * 64 + wn * 16 + l15;
#pragma unroll
        for (int g = 0; g < 4; ++g) bias[p][g] = w_b[g * HD + hh] + r_b[g * HD + hh];
    }

    // tile-0 prologue: stage kt 0,1,2 (order A0,B0,A1,B1,A2,B2)
    const short* gA = wsA + (size_t)(li * KTILES) * 8192 + t * 8;            // bm=li
    const short* gB = wsB + (size_t)((xcd * 2) * KTILES) * 8192 + t * 8;     // bh=2*xcd
#pragma unroll
    for (int kt = 0; kt < 3; ++kt) {
        gload16(gA + kt * 8192,        &S[kt][wid * 512]);
        gload16(gA + kt * 8192 + 4096, &S[kt][4096 + wid * 512]);
        gload16(gB + kt * 8192,        &S[kt][8192 + wid * 512]);
        gload16(gB + kt * 8192 + 4096, &S[kt][12288 + wid * 512]);
    }

    const size_t PL = (size_t)NB * HD;

    for (int tile = 0; tile < 4; ++tile) {
        const int bm = li + 32 * (tile >> 1);      // 0..63
        const int bh = xcd * 2 + (tile & 1);       // 0..15
        const int h  = bh * 64 + wn * 16 + l15;

        f32x4 acc[8][4];
#pragma unroll
        for (int g = 0; g < 4; ++g) {
            const float bv = bias[tile & 1][g];
            const f32x4 binit = {bv, bv, bv, bv};
#pragma unroll
            for (int mi = 0; mi < 8; ++mi) acc[mi][g] = binit;
        }

        const short* stA = gA + 3 * 8192;
        const short* stB = gB + 3 * 8192;

        for (int it = 0; it < 11; ++it) {          // kt = 4it .. 4it+3
            kstep<8, true>(S, 0, stA, stB, aoff, boff, wid, acc);
            kstep<8, true>(S, 1, stA, stB, aoff, boff, wid, acc);
            kstep<8, true>(S, 2, stA, stB, aoff, boff, wid, acc);
            kstep<8, true>(S, 3, stA, stB, aoff, boff, wid, acc);
        }
        kstep<8, true >(S, 0, stA, stB, aoff, boff, wid, acc);  // kt=44 stages 47
        kstep<8, false>(S, 1, stA, stB, aoff, boff, wid, acc);  // kt=45
        kstep<4, false>(S, 2, stA, stB, aoff, boff, wid, acc);  // kt=46
        kstep<0, false>(S, 3, stA, stB, aoff, boff, wid, acc);  // kt=47

        __builtin_amdgcn_s_barrier();              // protect slots vs next prologue
        __builtin_amdgcn_sched_barrier(0);

        // ---- fused epilogue (before next prologue: read-waits can't drain DMAs)
#pragma unroll
        for (int mi = 0; mi < 8; ++mi) {
#pragma unroll
            for (int r = 0; r < 4; ++r) {
                const int row = bm * 256 + wm * 128 + mi * 16 + l4 * 4 + r;
                const size_t idx = (size_t)row * HD + h;
                const float ci = acc[mi][0][r];
                const float ig = acc[mi][1][r];
                const float fg = acc[mi][2][r];
                const float og = acc[mi][3][r];
                const float mp  = m_p[idx];
                const float cp  = c_p[idx];
                const float np_ = n_p[idx];
                const float z  = tanhf(ci);
                const float it_ = expf(ig);
                const float mt = fmaxf(fg + mp, ig);
                const float sf = expf(fg + mp - mt);
                const float si = expf(ig - mt);
                const float ct = sf * cp + it_ * z;
                const float nt = sf * np_ + si;
                const float ot = 1.0f / (1.0f + expf(-og));
                const float ht = ot * (ct / nt);
                out[idx]          = ht;
                out[PL + idx]     = ct;
                out[2 * PL + idx] = ht;
                out[3 * PL + idx] = nt;
                out[4 * PL + idx] = mt;
            }
        }

        // ---- next tile's prologue (issued last; stores keep draining under it)
        if (tile < 3) {
            const int nbm = li + 32 * ((tile + 1) >> 1);
            const int nbh = xcd * 2 + ((tile + 1) & 1);
            gA = wsA + (size_t)(nbm * KTILES) * 8192 + t * 8;
            gB = wsB + (size_t)(nbh * KTILES) * 8192 + t * 8;
#pragma unroll
            for (int kt = 0; kt < 3; ++kt) {
                gload16(gA + kt * 8192,        &S[kt][wid * 512]);
                gload16(gA + kt * 8192 + 4096, &S[kt][4096 + wid * 512]);
                gload16(gB + kt * 8192,        &S[kt][8192 + wid * 512]);
                gload16(gB + kt * 8192 + 4096, &S[kt][12288 + wid * 512]);
            }
        }
    }
}

extern "C" void kernel_launch(void* const* d_in, const int* in_sizes, int n_in,
                              void* d_out, int out_size, void* d_ws, size_t ws_size,
                              hipStream_t stream) {
    const float* x   = (const float*)d_in[0];
    const float* c_p = (const float*)d_in[1];
    const float* h_p = (const float*)d_in[2];
    const float* n_p = (const float*)d_in[3];
    const float* m_p = (const float*)d_in[4];
    const float* w_w = (const float*)d_in[5];
    const float* w_b = (const float*)d_in[6];
    const float* r_w = (const float*)d_in[7];
    const float* r_b = (const float*)d_in[8];
    float* out = (float*)d_out;

    short* wsB = (short*)d_ws;                                         // 12.58 MB
    short* wsA = (short*)((char*)d_ws + (size_t)16 * KTILES * 16384);  // 50.33 MB

    prep_w<<<dim3(16 * KTILES), 256, 0, stream>>>(w_w, r_w, wsB);
    prep_a<<<dim3(64 * KTILES), NT, 0, stream>>>(x, h_p, wsA);
    slstm_fused<<<dim3(256), NT, 0, stream>>>(wsA, wsB, c_p, n_p, m_p, w_b, r_b, out);
}

// Round 6
// 328.554 us; speedup vs baseline: 1.1057x; 1.0207x over previous
//
#include <hip/hip_runtime.h>
#include <hip/hip_bf16.h>

typedef short bf16x8 __attribute__((ext_vector_type(8)));
typedef float f32x4 __attribute__((ext_vector_type(4)));

#define NB 16384
#define IN_DIM 512
#define HD 1024
#define NT 512
#define KTILES 48

__device__ __forceinline__ short f2b(float f) {
    __hip_bfloat16 h = __float2bfloat16(f);
    return *reinterpret_cast<short*>(&h);
}

__device__ __forceinline__ void gload16(const void* g, void* l) {
    __builtin_amdgcn_global_load_lds(
        (const __attribute__((address_space(1))) void*)g,
        (__attribute__((address_space(3))) void*)l, 16, 0, 0);
}

// fast transcendentals: v_exp_f32 / v_rcp_f32 (compiler handles hazards)
__device__ __forceinline__ float fexp(float x)  { return __expf(x); }
__device__ __forceinline__ float frcp(float x)  { return __builtin_amdgcn_rcpf(x); }

// ---------------- prepass: weights -> bf16 swizzled tiles (verified r2/r3) ---
__global__ void prep_w(const float* __restrict__ w_w, const float* __restrict__ r_w,
                       short* __restrict__ wsB) {
    const int blk = blockIdx.x;          // bh*48 + kt
    const int kt  = blk % KTILES;
    const int cid = threadIdx.x;         // 0..255
    const int bh  = blk / KTILES;
    const int g   = (cid >> 4) & 3;
    const int jh  = ((cid >> 6) << 4) | (cid & 15);
    const int gcol = g * HD + bh * 64 + jh;

    const float* src = (kt < 16) ? w_w : r_w;
    const int kbase  = (kt < 16) ? kt * 32 : (kt - 16) * 32;

    float v[32];
#pragma unroll
    for (int kk = 0; kk < 32; ++kk)
        v[kk] = src[(size_t)(kbase + kk) * 4096 + gcol];

    char* tile = (char*)(wsB + (size_t)blk * 8192);
    const int swz = ((cid >> 1) & 3) << 4;
#pragma unroll
    for (int s = 0; s < 4; ++s) {
        bf16x8 o;
#pragma unroll
        for (int j = 0; j < 8; ++j) o[j] = f2b(v[s * 8 + j]);
        *(bf16x8*)(tile + cid * 64 + ((s * 16) ^ swz)) = o;
    }
}

// ---------------- prepass: activations -> bf16 swizzled tiles (verified r3) --
__global__ void prep_a(const float* __restrict__ x, const float* __restrict__ h_p,
                       short* __restrict__ wsA) {
    const int blk  = blockIdx.x;         // bm*48 + kt
    const int kt   = blk % KTILES;
    const int bm   = blk / KTILES;
    const int t    = threadIdx.x;        // 0..511
    const int row  = t >> 1;             // 0..255
    const int half = t & 1;
    const int grow = bm * 256 + row;

    const float* src = (kt < 16)
        ? x   + (size_t)grow * IN_DIM + kt * 32 + half * 16
        : h_p + (size_t)grow * HD     + (kt - 16) * 32 + half * 16;

    float4 a0 = ((const float4*)src)[0];
    float4 a1 = ((const float4*)src)[1];
    float4 a2 = ((const float4*)src)[2];
    float4 a3 = ((const float4*)src)[3];
    float v[16] = {a0.x,a0.y,a0.z,a0.w, a1.x,a1.y,a1.z,a1.w,
                   a2.x,a2.y,a2.z,a2.w, a3.x,a3.y,a3.z,a3.w};

    char* tile = (char*)(wsA + (size_t)blk * 8192);
    const int swz = ((row >> 1) & 3) << 4;
#pragma unroll
    for (int s = 0; s < 2; ++s) {
        bf16x8 o;
#pragma unroll
        for (int j = 0; j < 8; ++j) o[j] = f2b(v[s * 8 + j]);
        *(bf16x8*)(tile + row * 64 + ((half * 32 + s * 16) ^ swz)) = o;
    }
}

// ---------------- main: persistent, 256x256 tile, counted-vmcnt pipeline -----
template<int VM, bool STAGE>
__device__ __forceinline__ void kstep(short (*S)[16384], int slot,
                                      const short*& stA, const short*& stB,
                                      int aoff, int boff, int wid,
                                      f32x4 (&acc)[8][4]) {
    if constexpr (VM == 8)      asm volatile("s_waitcnt vmcnt(8)" ::: "memory");
    else if constexpr (VM == 4) asm volatile("s_waitcnt vmcnt(4)" ::: "memory");
    else                        asm volatile("s_waitcnt vmcnt(0)" ::: "memory");
    __builtin_amdgcn_s_barrier();
    __builtin_amdgcn_sched_barrier(0);

    const short* Sc = S[slot];
    const int js = (slot + 3) & 3;

    bf16x8 bfr[4], af[4];
#pragma unroll
    for (int g = 0; g < 4; ++g)    bfr[g] = *(const bf16x8*)&Sc[boff + g * 512];
#pragma unroll
    for (int mi = 0; mi < 4; ++mi) af[mi] = *(const bf16x8*)&Sc[aoff + mi * 512];
    if constexpr (STAGE) {
        gload16(stA,        &S[js][wid * 512]);
        gload16(stA + 4096, &S[js][4096 + wid * 512]);
    }
    __builtin_amdgcn_s_setprio(1);
#pragma unroll
    for (int mi = 0; mi < 4; ++mi)
#pragma unroll
        for (int g = 0; g < 4; ++g)
            acc[mi][g] = __builtin_amdgcn_mfma_f32_16x16x32_bf16(
                af[mi], bfr[g], acc[mi][g], 0, 0, 0);
    __builtin_amdgcn_s_setprio(0);

#pragma unroll
    for (int mi = 0; mi < 4; ++mi) af[mi] = *(const bf16x8*)&Sc[aoff + (mi + 4) * 512];
    if constexpr (STAGE) {
        gload16(stB,        &S[js][8192 + wid * 512]);
        gload16(stB + 4096, &S[js][12288 + wid * 512]);
        stA += 8192; stB += 8192;
    }
    __builtin_amdgcn_s_setprio(1);
#pragma unroll
    for (int mi = 0; mi < 4; ++mi)
#pragma unroll
        for (int g = 0; g < 4; ++g)
            acc[mi + 4][g] = __builtin_amdgcn_mfma_f32_16x16x32_bf16(
                af[mi], bfr[g], acc[mi + 4][g], 0, 0, 0);
    __builtin_amdgcn_s_setprio(0);
}

__global__ __launch_bounds__(NT, 2) void slstm_fused(
    const short* __restrict__ wsA, const short* __restrict__ wsB,
    const float* __restrict__ c_p, const float* __restrict__ n_p,
    const float* __restrict__ m_p, const float* __restrict__ w_b,
    const float* __restrict__ r_b, float* __restrict__ out)
{
    __shared__ __align__(16) short S[4][16384];   // 128 KiB, 4 rotating kt-slots

    const int t    = threadIdx.x;
    const int lane = t & 63;
    const int wid  = t >> 6;     // 0..7
    const int wm   = wid >> 2;   // 0..1
    const int wn   = wid & 3;    // 0..3
    const int l15  = lane & 15;
    const int l4   = lane >> 4;

    const int b   = (int)blockIdx.x;   // 0..255, persistent (1/CU)
    const int xcd = b & 7;
    const int li  = b >> 3;            // 0..31

    const int sw   = (l4 * 8) ^ (((l15 >> 1) & 3) << 3);
    const int aoff = (wm * 128 + l15) * 32 + sw;           // + mi*512
    const int boff = 8192 + (wn * 64 + l15) * 32 + sw;     // + g*512

    // two bias sets (bh parity), hoisted
    float bias[2][4];
#pragma unroll
    for (int p = 0; p < 2; ++p) {
        const int hh = (xcd * 2 + p) * 64 + wn * 16 + l15;
#pragma unroll
        for (int g = 0; g < 4; ++g) bias[p][g] = w_b[g * HD + hh] + r_b[g * HD + hh];
    }

    // tile-0 prologue: stage kt 0,1,2
    const short* gA = wsA + (size_t)(li * KTILES) * 8192 + t * 8;            // bm=li
    const short* gB = wsB + (size_t)((xcd * 2) * KTILES) * 8192 + t * 8;     // bh=2*xcd
#pragma unroll
    for (int kt = 0; kt < 3; ++kt) {
        gload16(gA + kt * 8192,        &S[kt][wid * 512]);
        gload16(gA + kt * 8192 + 4096, &S[kt][4096 + wid * 512]);
        gload16(gB + kt * 8192,        &S[kt][8192 + wid * 512]);
        gload16(gB + kt * 8192 + 4096, &S[kt][12288 + wid * 512]);
    }

    const size_t PL = (size_t)NB * HD;

    for (int tile = 0; tile < 4; ++tile) {
        const int bm = li + 32 * (tile >> 1);      // 0..63
        const int bh = xcd * 2 + (tile & 1);       // 0..15
        const int h  = bh * 64 + wn * 16 + l15;

        f32x4 acc[8][4];
#pragma unroll
        for (int g = 0; g < 4; ++g) {
            const float bv = bias[tile & 1][g];
            const f32x4 binit = {bv, bv, bv, bv};
#pragma unroll
            for (int mi = 0; mi < 8; ++mi) acc[mi][g] = binit;
        }

        const short* stA = gA + 3 * 8192;
        const short* stB = gB + 3 * 8192;

        for (int it = 0; it < 11; ++it) {          // kt = 4it .. 4it+3
            kstep<8, true>(S, 0, stA, stB, aoff, boff, wid, acc);
            kstep<8, true>(S, 1, stA, stB, aoff, boff, wid, acc);
            kstep<8, true>(S, 2, stA, stB, aoff, boff, wid, acc);
            kstep<8, true>(S, 3, stA, stB, aoff, boff, wid, acc);
        }
        kstep<8, true >(S, 0, stA, stB, aoff, boff, wid, acc);  // kt=44 stages 47
        kstep<8, false>(S, 1, stA, stB, aoff, boff, wid, acc);  // kt=45
        kstep<4, false>(S, 2, stA, stB, aoff, boff, wid, acc);  // kt=46
        kstep<0, false>(S, 3, stA, stB, aoff, boff, wid, acc);  // kt=47

        __builtin_amdgcn_s_barrier();              // protect slots vs next prologue
        __builtin_amdgcn_sched_barrier(0);

        // ---- fused epilogue, native transcendentals ----
#pragma unroll
        for (int mi = 0; mi < 8; ++mi) {
#pragma unroll
            for (int r = 0; r < 4; ++r) {
                const int row = bm * 256 + wm * 128 + mi * 16 + l4 * 4 + r;
                const size_t idx = (size_t)row * HD + h;
                const float ci = acc[mi][0][r];
                const float ig = acc[mi][1][r];
                const float fg = acc[mi][2][r];
                const float og = acc[mi][3][r];
                const float mp  = m_p[idx];
                const float cp  = c_p[idx];
                const float np_ = n_p[idx];
                // tanh(ci) via exp(-2|ci|), sign-restored
                const float e2 = fexp(-2.0f * fabsf(ci));
                const float zt = (1.0f - e2) * frcp(1.0f + e2);
                const float z  = copysignf(zt, ci);
                const float it_ = fexp(ig);
                const float mt = fmaxf(fg + mp, ig);
                const float sf = fexp(fg + mp - mt);   // arg <= 0
                const float si = fexp(ig - mt);        // arg <= 0
                const float ct = sf * cp + it_ * z;
                const float nt = sf * np_ + si;
                const float ot = frcp(1.0f + fexp(-og));
                const float ht = ot * ct * frcp(nt);
                out[idx]          = ht;
                out[PL + idx]     = ct;
                out[2 * PL + idx] = ht;
                out[3 * PL + idx] = nt;
                out[4 * PL + idx] = mt;
            }
        }

        // ---- next tile's prologue (stores keep draining under it)
        if (tile < 3) {
            const int nbm = li + 32 * ((tile + 1) >> 1);
            const int nbh = xcd * 2 + ((tile + 1) & 1);
            gA = wsA + (size_t)(nbm * KTILES) * 8192 + t * 8;
            gB = wsB + (size_t)(nbh * KTILES) * 8192 + t * 8;
#pragma unroll
            for (int kt = 0; kt < 3; ++kt) {
                gload16(gA + kt * 8192,        &S[kt][wid * 512]);
                gload16(gA + kt * 8192 + 4096, &S[kt][4096 + wid * 512]);
                gload16(gB + kt * 8192,        &S[kt][8192 + wid * 512]);
                gload16(gB + kt * 8192 + 4096, &S[kt][12288 + wid * 512]);
            }
        }
    }
}

extern "C" void kernel_launch(void* const* d_in, const int* in_sizes, int n_in,
                              void* d_out, int out_size, void* d_ws, size_t ws_size,
                              hipStream_t stream) {
    const float* x   = (const float*)d_in[0];
    const float* c_p = (const float*)d_in[1];
    const float* h_p = (const float*)d_in[2];
    const float* n_p = (const float*)d_in[3];
    const float* m_p = (const float*)d_in[4];
    const float* w_w = (const float*)d_in[5];
    const float* w_b = (const float*)d_in[6];
    const float* r_w = (const float*)d_in[7];
    const float* r_b = (const float*)d_in[8];
    float* out = (float*)d_out;

    short* wsB = (short*)d_ws;                                         // 12.58 MB
    short* wsA = (short*)((char*)d_ws + (size_t)16 * KTILES * 16384);  // 50.33 MB

    prep_w<<<dim3(16 * KTILES), 256, 0, stream>>>(w_w, r_w, wsB);
    prep_a<<<dim3(64 * KTILES), NT, 0, stream>>>(x, h_p, wsA);
    slstm_fused<<<dim3(256), NT, 0, stream>>>(wsA, wsB, c_p, n_p, m_p, w_b, r_b, out);
}